// Round 1
// baseline (1555.693 us; speedup 1.0000x reference)
//
#include <hip/hip_runtime.h>
#include <hip/hip_bf16.h>

#define B_ 2
#define S_ 2048
#define D_ 4096
#define NH_ 32
#define NKV_ 8
#define HD_ 128
#define M_ (B_ * S_)

typedef __bf16 bf16x8_t __attribute__((ext_vector_type(8)));
typedef __bf16 bf16x2_t __attribute__((ext_vector_type(2)));
typedef float f32x4_t __attribute__((ext_vector_type(4)));

// ---------------- GEMM: C[M][N] = X[M][K] * W[N][K]^T ----------------
// 128x128 tile, BK=32, 4 waves, each wave 64x64 via 4x4 mfma_16x16x32_bf16
template <bool XF32, bool OUTF32>
__global__ __launch_bounds__(256) void gemm_xt(const void* __restrict__ Xv,
                                               const float* __restrict__ W,
                                               void* __restrict__ Cv,
                                               int N, int K) {
  // +8 pad: row stride 40 bf16 = 80B (5x16B aligned, 2-way bank alias = free)
  __shared__ __attribute__((aligned(16))) __bf16 As[128][40];
  __shared__ __attribute__((aligned(16))) __bf16 Bs[128][40];
  const int tid = threadIdx.x;
  const int lane = tid & 63;
  const int wid = tid >> 6;
  const int wm = (wid & 1) * 64;
  const int wn = (wid >> 1) * 64;
  const int m0 = blockIdx.y * 128;
  const int n0 = blockIdx.x * 128;
  const int lo = lane & 15;
  const int hi = lane >> 4;

  f32x4_t acc[4][4] = {};

  const int rr0 = tid >> 2;  // 0..63
  const int kc = tid & 3;    // k chunk of 8

  for (int k0 = 0; k0 < K; k0 += 32) {
#pragma unroll
    for (int hh = 0; hh < 2; hh++) {
      const int rr = rr0 + hh * 64;
      // stage A (convert to bf16 if fp32 input)
      bf16x8_t ta;
      if constexpr (XF32) {
        const float* src = (const float*)Xv + (size_t)(m0 + rr) * K + k0 + kc * 8;
        const float4* s4 = reinterpret_cast<const float4*>(src);
        float4 v0 = s4[0], v1 = s4[1];
        ta[0] = (__bf16)v0.x; ta[1] = (__bf16)v0.y; ta[2] = (__bf16)v0.z; ta[3] = (__bf16)v0.w;
        ta[4] = (__bf16)v1.x; ta[5] = (__bf16)v1.y; ta[6] = (__bf16)v1.z; ta[7] = (__bf16)v1.w;
      } else {
        const __bf16* src = (const __bf16*)Xv + (size_t)(m0 + rr) * K + k0 + kc * 8;
        ta = *reinterpret_cast<const bf16x8_t*>(src);
      }
      *reinterpret_cast<bf16x8_t*>(&As[rr][kc * 8]) = ta;
      // stage B (W always fp32)
      const float* srcb = W + (size_t)(n0 + rr) * K + k0 + kc * 8;
      const float4* sb4 = reinterpret_cast<const float4*>(srcb);
      float4 b0 = sb4[0], b1 = sb4[1];
      bf16x8_t tb;
      tb[0] = (__bf16)b0.x; tb[1] = (__bf16)b0.y; tb[2] = (__bf16)b0.z; tb[3] = (__bf16)b0.w;
      tb[4] = (__bf16)b1.x; tb[5] = (__bf16)b1.y; tb[6] = (__bf16)b1.z; tb[7] = (__bf16)b1.w;
      *reinterpret_cast<bf16x8_t*>(&Bs[rr][kc * 8]) = tb;
    }
    __syncthreads();
    bf16x8_t af[4], bfr[4];
#pragma unroll
    for (int mi = 0; mi < 4; mi++)
      af[mi] = *reinterpret_cast<const bf16x8_t*>(&As[wm + mi * 16 + lo][hi * 8]);
#pragma unroll
    for (int ni = 0; ni < 4; ni++)
      bfr[ni] = *reinterpret_cast<const bf16x8_t*>(&Bs[wn + ni * 16 + lo][hi * 8]);
#pragma unroll
    for (int mi = 0; mi < 4; mi++)
#pragma unroll
      for (int ni = 0; ni < 4; ni++)
        acc[mi][ni] = __builtin_amdgcn_mfma_f32_16x16x32_bf16(af[mi], bfr[ni], acc[mi][ni], 0, 0, 0);
    __syncthreads();
  }
  // epilogue: D layout col=lane&15, row=(lane>>4)*4+r  [m89/m91 verified]
#pragma unroll
  for (int mi = 0; mi < 4; mi++) {
    const int mrow = m0 + wm + mi * 16 + hi * 4;
#pragma unroll
    for (int ni = 0; ni < 4; ni++) {
      const int ncol = n0 + wn + ni * 16 + lo;
#pragma unroll
      for (int r = 0; r < 4; r++) {
        if constexpr (OUTF32)
          ((float*)Cv)[(size_t)(mrow + r) * N + ncol] = acc[mi][ni][r];
        else
          ((__bf16*)Cv)[(size_t)(mrow + r) * N + ncol] = (__bf16)acc[mi][ni][r];
      }
    }
  }
}

// ---------------- RoPE (in-place on bf16 q and k) ----------------
__global__ __launch_bounds__(256) void rope_kernel(__bf16* __restrict__ q,
                                                   __bf16* __restrict__ k,
                                                   const float* __restrict__ fcos,
                                                   const float* __restrict__ fsin) {
  const int p = blockIdx.x * 256 + threadIdx.x;
  const int j = p & 63;
  int rem = p >> 6;
  const int hh = rem % (NH_ + NKV_);
  rem /= (NH_ + NKV_);
  const int s = rem % S_;
  const int b = rem / S_;
  const float c = fcos[s * 64 + j];
  const float sn = fsin[s * 64 + j];
  __bf16* base;
  if (hh < NH_)
    base = q + ((size_t)(b * S_ + s) * NH_ + hh) * HD_ + 2 * j;
  else
    base = k + ((size_t)(b * S_ + s) * NKV_ + (hh - NH_)) * HD_ + 2 * j;
  bf16x2_t xv = *reinterpret_cast<const bf16x2_t*>(base);
  const float xe = (float)xv[0], xo = (float)xv[1];
  bf16x2_t ov;
  ov[0] = (__bf16)(xe * c - xo * sn);
  ov[1] = (__bf16)(xe * sn + xo * c);
  *reinterpret_cast<bf16x2_t*>(base) = ov;
}

// ---------------- Flash attention (causal, GQA) ----------------
// block: 64 q-rows x 1 head x 1 batch; 4 waves, wave w owns q rows [16w,16w+16)
__global__ __launch_bounds__(256) void attn_kernel(const __bf16* __restrict__ q,
                                                   const __bf16* __restrict__ k,
                                                   const __bf16* __restrict__ v,
                                                   __bf16* __restrict__ o) {
  const int qt = blockIdx.x;
  const int h = blockIdx.y;
  const int b = blockIdx.z;
  const int hkv = h >> 2;  // N_REP = 4
  const int tid = threadIdx.x;
  const int lane = tid & 63;
  const int w = tid >> 6;
  const int q0 = qt * 64;
  const int lo = lane & 15;
  const int hi = lane >> 4;

  __shared__ __attribute__((aligned(16))) __bf16 Ks[64][136];   // [key][k], pad 128->136
  __shared__ __attribute__((aligned(16))) __bf16 Vt[128][72];   // [hd][key], pad 64->72
  __shared__ __attribute__((aligned(16))) __bf16 Ps[4][16][72]; // per-wave P, pad 64->72

  // Q fragments (A-layout: m=lane&15, k=hi*8+j within 32-step), 4 k-steps over HD=128
  bf16x8_t qf[4];
  {
    const size_t qbase = ((size_t)(b * S_ + q0 + w * 16 + lo) * NH_ + h) * HD_;
#pragma unroll
    for (int ks = 0; ks < 4; ks++)
      qf[ks] = *reinterpret_cast<const bf16x8_t*>(q + qbase + ks * 32 + hi * 8);
  }

  f32x4_t o_acc[8] = {};
  float m_prev[4], l_sum[4];
#pragma unroll
  for (int r = 0; r < 4; r++) { m_prev[r] = -1e30f; l_sum[r] = 0.f; }

  constexpr float scale = 0.08838834764831845f;  // 1/sqrt(128)
  constexpr float L2E = 1.44269504088896f;

  for (int kt = 0; kt <= qt; kt++) {
    const int kt0 = kt * 64;
    __syncthreads();  // previous tile's LDS reads done
    // stage K tile [64][128]
#pragma unroll
    for (int i = 0; i < 4; i++) {
      const int c = tid + i * 256;
      const int key = c >> 4, hc = c & 15;
      const __bf16* src = k + ((size_t)(b * S_ + kt0 + key) * NKV_ + hkv) * HD_ + hc * 8;
      *reinterpret_cast<bf16x8_t*>(&Ks[key][hc * 8]) = *reinterpret_cast<const bf16x8_t*>(src);
    }
    // stage V tile transposed -> Vt[hd][key]
#pragma unroll
    for (int i = 0; i < 4; i++) {
      const int c = tid + i * 256;
      const int key = c & 63, hc = c >> 6;
      const __bf16* src = v + ((size_t)(b * S_ + kt0 + key) * NKV_ + hkv) * HD_ + hc * 8;
      bf16x8_t vv = *reinterpret_cast<const bf16x8_t*>(src);
#pragma unroll
      for (int e = 0; e < 8; e++) Vt[hc * 8 + e][key] = vv[e];
    }
    __syncthreads();

    // S = Q K^T : 4 n-subtiles (keys), 4 k-steps
    f32x4_t s_acc[4] = {};
#pragma unroll
    for (int ks = 0; ks < 4; ks++) {
#pragma unroll
      for (int t = 0; t < 4; t++) {
        bf16x8_t kf = *reinterpret_cast<const bf16x8_t*>(&Ks[t * 16 + lo][ks * 32 + hi * 8]);
        s_acc[t] = __builtin_amdgcn_mfma_f32_16x16x32_bf16(qf[ks], kf, s_acc[t], 0, 0, 0);
      }
    }

    // scale + causal mask (diagonal tile only)
    float sv[4][4];
    const bool diag = (kt == qt);
#pragma unroll
    for (int t = 0; t < 4; t++) {
#pragma unroll
      for (int r = 0; r < 4; r++) {
        float val = s_acc[t][r] * scale;
        if (diag) {
          const int key = kt0 + t * 16 + lo;
          const int qr = q0 + w * 16 + hi * 4 + r;
          if (key > qr) val = -1e30f;
        }
        sv[t][r] = val;
      }
    }
    // online softmax: rows live on 16-lane groups (same hi), cols = lo
    float mnew[4], alpha[4];
#pragma unroll
    for (int r = 0; r < 4; r++) {
      float mx = fmaxf(fmaxf(sv[0][r], sv[1][r]), fmaxf(sv[2][r], sv[3][r]));
#pragma unroll
      for (int off = 1; off < 16; off <<= 1) mx = fmaxf(mx, __shfl_xor(mx, off));
      mnew[r] = fmaxf(m_prev[r], mx);
      alpha[r] = exp2f((m_prev[r] - mnew[r]) * L2E);
      m_prev[r] = mnew[r];
    }
#pragma unroll
    for (int r = 0; r < 4; r++) {
      float srow = 0.f;
#pragma unroll
      for (int t = 0; t < 4; t++) {
        const float pv = exp2f((sv[t][r] - mnew[r]) * L2E);
        sv[t][r] = pv;
        srow += pv;
      }
#pragma unroll
      for (int off = 1; off < 16; off <<= 1) srow += __shfl_xor(srow, off);
      l_sum[r] = l_sum[r] * alpha[r] + srow;
    }
#pragma unroll
    for (int t8 = 0; t8 < 8; t8++) {
#pragma unroll
      for (int r = 0; r < 4; r++) o_acc[t8][r] *= alpha[r];
    }
    // P: D-layout -> LDS -> A-layout (per-wave region, in-wave lgkmcnt ordering)
#pragma unroll
    for (int t = 0; t < 4; t++)
#pragma unroll
      for (int r = 0; r < 4; r++)
        Ps[w][hi * 4 + r][t * 16 + lo] = (__bf16)sv[t][r];

    // O += P V : K-dim 64 keys = 2 k-steps; 8 n-subtiles over HD=128
#pragma unroll
    for (int ks2 = 0; ks2 < 2; ks2++) {
      bf16x8_t pf = *reinterpret_cast<const bf16x8_t*>(&Ps[w][lo][ks2 * 32 + hi * 8]);
#pragma unroll
      for (int t8 = 0; t8 < 8; t8++) {
        bf16x8_t vf = *reinterpret_cast<const bf16x8_t*>(&Vt[t8 * 16 + lo][ks2 * 32 + hi * 8]);
        o_acc[t8] = __builtin_amdgcn_mfma_f32_16x16x32_bf16(pf, vf, o_acc[t8], 0, 0, 0);
      }
    }
  }

  // epilogue: divide by l, store bf16 attn_out (b, s, h, hd)
#pragma unroll
  for (int r = 0; r < 4; r++) {
    const float inv = 1.0f / l_sum[r];
    const int qr = q0 + w * 16 + hi * 4 + r;
    const size_t obase = ((size_t)(b * S_ + qr) * NH_ + h) * HD_;
#pragma unroll
    for (int t8 = 0; t8 < 8; t8++)
      o[obase + t8 * 16 + lo] = (__bf16)(o_acc[t8][r] * inv);
  }
}

extern "C" void kernel_launch(void* const* d_in, const int* in_sizes, int n_in,
                              void* d_out, int out_size, void* d_ws, size_t ws_size,
                              hipStream_t stream) {
  const float* x = (const float*)d_in[0];
  const float* wq = (const float*)d_in[1];
  const float* wk = (const float*)d_in[2];
  const float* wv = (const float*)d_in[3];
  const float* wo = (const float*)d_in[4];
  const float* fcos = (const float*)d_in[5];
  const float* fsin = (const float*)d_in[6];
  // d_in[7] mask (implicit causal), d_in[8..9] zero caches, d_in[10] start_pos=0: unused
  float* out = (float*)d_out;

  __bf16* qb = (__bf16*)d_ws;                      // (B,S,NH,HD)  bf16  33.5MB
  __bf16* kb = qb + (size_t)M_ * NH_ * HD_;        // (B,S,NKV,HD) bf16   8.4MB
  __bf16* vb = kb + (size_t)M_ * NKV_ * HD_;       // (B,S,NKV,HD) bf16   8.4MB
  __bf16* ab = vb + (size_t)M_ * NKV_ * HD_;       // (B,S,NH,HD)  bf16  33.5MB

  gemm_xt<true, false><<<dim3((NH_ * HD_) / 128, M_ / 128), 256, 0, stream>>>(x, wq, qb, NH_ * HD_, D_);
  gemm_xt<true, false><<<dim3((NKV_ * HD_) / 128, M_ / 128), 256, 0, stream>>>(x, wk, kb, NKV_ * HD_, D_);
  gemm_xt<true, false><<<dim3((NKV_ * HD_) / 128, M_ / 128), 256, 0, stream>>>(x, wv, vb, NKV_ * HD_, D_);
  rope_kernel<<<(M_ * (NH_ + NKV_) * (HD_ / 2)) / 256, 256, 0, stream>>>(qb, kb, fcos, fsin);
  attn_kernel<<<dim3(S_ / 64, NH_, B_), 256, 0, stream>>>(qb, kb, vb, ab);
  gemm_xt<false, true><<<dim3(D_ / 128, M_ / 128), 256, 0, stream>>>(ab, wo, out, D_, NH_ * HD_);
}

// Round 3
// 1114.434 us; speedup vs baseline: 1.3959x; 1.3959x over previous
//
#include <hip/hip_runtime.h>
#include <hip/hip_bf16.h>

#define B_ 2
#define S_ 2048
#define D_ 4096
#define NH_ 32
#define NKV_ 8
#define HD_ 128
#define M_ (B_ * S_)

typedef __bf16 bf16x8_t __attribute__((ext_vector_type(8)));
typedef float f32x4_t __attribute__((ext_vector_type(4)));

__device__ __forceinline__ void gload16(const __bf16* g, __bf16* l) {
  __builtin_amdgcn_global_load_lds(
      (const __attribute__((address_space(1))) void*)g,
      (__attribute__((address_space(3))) void*)l, 16, 0, 0);
}

// ---------------- fp32 -> bf16 converts ----------------
// x (16.7M) + wq (16.7M) + wk (4.2M) + wv (4.2M), 8 elts/thread
__global__ __launch_bounds__(256) void convert_main(const float* __restrict__ x,
                                                    const float* __restrict__ wq,
                                                    const float* __restrict__ wk,
                                                    const float* __restrict__ wv,
                                                    __bf16* __restrict__ xb,
                                                    __bf16* __restrict__ wqkv) {
  size_t c = (size_t)blockIdx.x * 256 + threadIdx.x;
  const float* src;
  __bf16* dst;
  if (c < 2097152) { src = x + c * 8; dst = xb + c * 8; }
  else if (c < 4194304) { c -= 2097152; src = wq + c * 8; dst = wqkv + c * 8; }
  else if (c < 4718592) { c -= 4194304; src = wk + c * 8; dst = wqkv + 16777216 + c * 8; }
  else { c -= 4718592; src = wv + c * 8; dst = wqkv + 20971520 + c * 8; }
  const float4* s4 = reinterpret_cast<const float4*>(src);
  float4 a = s4[0], b = s4[1];
  bf16x8_t t;
  t[0] = (__bf16)a.x; t[1] = (__bf16)a.y; t[2] = (__bf16)a.z; t[3] = (__bf16)a.w;
  t[4] = (__bf16)b.x; t[5] = (__bf16)b.y; t[6] = (__bf16)b.z; t[7] = (__bf16)b.w;
  *reinterpret_cast<bf16x8_t*>(dst) = t;
}

__global__ __launch_bounds__(256) void convert_wo(const float* __restrict__ wo,
                                                  __bf16* __restrict__ wob) {
  size_t c = (size_t)blockIdx.x * 256 + threadIdx.x;
  const float4* s4 = reinterpret_cast<const float4*>(wo + c * 8);
  float4 a = s4[0], b = s4[1];
  bf16x8_t t;
  t[0] = (__bf16)a.x; t[1] = (__bf16)a.y; t[2] = (__bf16)a.z; t[3] = (__bf16)a.w;
  t[4] = (__bf16)b.x; t[5] = (__bf16)b.y; t[6] = (__bf16)b.z; t[7] = (__bf16)b.w;
  *reinterpret_cast<bf16x8_t*>(wob + c * 8) = t;
}

// ---------------- GEMM (m97 structure): C = A[M][K] * Bm[N][K]^T ----------------
// 128x128 tile, BK=32, 4 waves 4x4 mfma_16x16x32_bf16, global_load_lds width 16
template <bool SPLIT, bool OUTF32>
__global__ __launch_bounds__(256) void gemm_bt(const __bf16* __restrict__ A,
                                               const __bf16* __restrict__ Bm,
                                               void* __restrict__ C0,
                                               void* __restrict__ C1,
                                               int N, int K) {
  __shared__ __attribute__((aligned(16))) __bf16 As[128 * 32];  // unpadded: global_load_lds order
  __shared__ __attribute__((aligned(16))) __bf16 Bs[128 * 32];
  const int tid = threadIdx.x;
  const int lane = tid & 63;
  const int w = tid >> 6;
  const int lo = lane & 15;
  const int hi = lane >> 4;
  const int wm = (w & 1) * 64;
  const int wn = (w >> 1) * 64;
  const int m0 = blockIdx.y * 128;
  const int n0 = blockIdx.x * 128;

  // staging: lane l covers row l>>2, 16B chunk l&3 -> LDS offset == lane*16 (HW order)
  const int srow = w * 32 + (lane >> 2);
  const int scol = (lane & 3) * 8;
  const __bf16* ga0 = A + (size_t)(m0 + srow) * K + scol;
  const __bf16* ga1 = A + (size_t)(m0 + srow + 16) * K + scol;
  const __bf16* gb0 = Bm + (size_t)(n0 + srow) * K + scol;
  const __bf16* gb1 = Bm + (size_t)(n0 + srow + 16) * K + scol;
  __bf16* la0 = &As[(w * 32) * 32];
  __bf16* la1 = &As[(w * 32 + 16) * 32];
  __bf16* lb0 = &Bs[(w * 32) * 32];
  __bf16* lb1 = &Bs[(w * 32 + 16) * 32];

  f32x4_t acc[4][4] = {};

  for (int k0 = 0; k0 < K; k0 += 32) {
    __syncthreads();
    gload16(ga0 + k0, la0);
    gload16(ga1 + k0, la1);
    gload16(gb0 + k0, lb0);
    gload16(gb1 + k0, lb1);
    __syncthreads();  // drains vmcnt before barrier -> LDS valid
    bf16x8_t af[4], bfr[4];
#pragma unroll
    for (int mi = 0; mi < 4; mi++)
      af[mi] = *reinterpret_cast<const bf16x8_t*>(&As[(wm + mi * 16 + lo) * 32 + hi * 8]);
#pragma unroll
    for (int ni = 0; ni < 4; ni++)
      bfr[ni] = *reinterpret_cast<const bf16x8_t*>(&Bs[(wn + ni * 16 + lo) * 32 + hi * 8]);
#pragma unroll
    for (int mi = 0; mi < 4; mi++)
#pragma unroll
      for (int ni = 0; ni < 4; ni++)
        acc[mi][ni] = __builtin_amdgcn_mfma_f32_16x16x32_bf16(af[mi], bfr[ni], acc[mi][ni], 0, 0, 0);
  }

  // epilogue: D layout col=lane&15, row=(lane>>4)*4+r
  __bf16* Cb = nullptr;
  float* Cf = nullptr;
  int ldc, nb;
  if constexpr (SPLIT) {
    if (n0 < 4096) { Cb = (__bf16*)C0; ldc = 4096; nb = n0; }
    else { Cb = (__bf16*)C1; ldc = 2048; nb = n0 - 4096; }
  } else {
    ldc = N; nb = n0;
    if constexpr (OUTF32) Cf = (float*)C0; else Cb = (__bf16*)C0;
  }
#pragma unroll
  for (int mi = 0; mi < 4; mi++) {
    const int mrow = m0 + wm + mi * 16 + hi * 4;
#pragma unroll
    for (int ni = 0; ni < 4; ni++) {
      const int ncol = nb + wn + ni * 16 + lo;
#pragma unroll
      for (int r = 0; r < 4; r++) {
        if constexpr (OUTF32)
          Cf[(size_t)(mrow + r) * ldc + ncol] = acc[mi][ni][r];
        else
          Cb[(size_t)(mrow + r) * ldc + ncol] = (__bf16)acc[mi][ni][r];
      }
    }
  }
}

// ---------------- RoPE (in-place; q: (M,NH,HD), kv: (M,2048) K at hkv*128) ----------------
typedef __bf16 bf16x2_t __attribute__((ext_vector_type(2)));
__global__ __launch_bounds__(256) void rope_kernel(__bf16* __restrict__ q,
                                                   __bf16* __restrict__ kv,
                                                   const float* __restrict__ fcos,
                                                   const float* __restrict__ fsin) {
  const int p = blockIdx.x * 256 + threadIdx.x;
  const int j = p & 63;
  int rem = p >> 6;
  const int hh = rem % (NH_ + NKV_);
  rem /= (NH_ + NKV_);
  const int s = rem % S_;
  const int b = rem / S_;
  const float c = fcos[s * 64 + j];
  const float sn = fsin[s * 64 + j];
  __bf16* base;
  if (hh < NH_)
    base = q + ((size_t)(b * S_ + s) * NH_ + hh) * HD_ + 2 * j;
  else
    base = kv + (size_t)(b * S_ + s) * 2048 + (hh - NH_) * HD_ + 2 * j;
  bf16x2_t xv = *reinterpret_cast<const bf16x2_t*>(base);
  const float xe = (float)xv[0], xo = (float)xv[1];
  bf16x2_t ov;
  ov[0] = (__bf16)(xe * c - xo * sn);
  ov[1] = (__bf16)(xe * sn + xo * c);
  *reinterpret_cast<bf16x2_t*>(base) = ov;
}

// ---------------- Flash attention: 128 q-rows/block, 64-key tiles ----------------
__global__ __launch_bounds__(256) void attn_kernel(const __bf16* __restrict__ q,
                                                   const __bf16* __restrict__ kv,
                                                   __bf16* __restrict__ o) {
  const int qt = blockIdx.x;   // 16 tiles of 128 q-rows
  const int h = blockIdx.y;
  const int b = blockIdx.z;
  const int hkv = h >> 2;
  const int tid = threadIdx.x;
  const int lane = tid & 63;
  const int w = tid >> 6;
  const int lo = lane & 15;
  const int hi = lane >> 4;
  const int q0 = qt * 128;

  __shared__ __attribute__((aligned(16))) __bf16 Ks[64 * 132];   // [key][hd] pad 128->132
  __shared__ __attribute__((aligned(16))) __bf16 Vt[128 * 68];   // [hd][key] pad 64->68
  __shared__ __attribute__((aligned(16))) __bf16 Ps[4][32 * 68]; // per-wave P (32 rows)

  // Q fragments: wave w owns rows q0+w*32 .. +32 (2 m-frags)
  bf16x8_t qf[2][4];
#pragma unroll
  for (int mi = 0; mi < 2; mi++) {
    const size_t qbase = ((size_t)(b * S_ + q0 + w * 32 + mi * 16 + lo) * NH_ + h) * HD_;
#pragma unroll
    for (int ks = 0; ks < 4; ks++)
      qf[mi][ks] = *reinterpret_cast<const bf16x8_t*>(q + qbase + ks * 32 + hi * 8);
  }

  f32x4_t o_acc[2][8] = {};
  f32x4_t l_acc[2] = {};
  float m_prev[2][4];
#pragma unroll
  for (int mi = 0; mi < 2; mi++)
#pragma unroll
    for (int r = 0; r < 4; r++) m_prev[mi][r] = -1e30f;

  bf16x8_t ones;
#pragma unroll
  for (int e = 0; e < 8; e++) ones[e] = (__bf16)1.0f;

  constexpr float SC = 0.08838834764831845f * 1.44269504088896f;  // scale * log2(e)

  const int nkt = qt * 2 + 2;
  for (int kt = 0; kt < nkt; kt++) {
    const int kt0 = kt * 64;
    __syncthreads();
    // stage K [64][128]
#pragma unroll
    for (int i = 0; i < 4; i++) {
      const int c = tid + i * 256;
      const int key = c >> 4, hc = c & 15;
      *reinterpret_cast<bf16x8_t*>(&Ks[key * 132 + hc * 8]) =
          *reinterpret_cast<const bf16x8_t*>(kv + (size_t)(b * S_ + kt0 + key) * 2048 + hkv * 128 + hc * 8);
    }
    // stage V transposed -> Vt[hd][key]
#pragma unroll
    for (int i = 0; i < 4; i++) {
      const int c = tid + i * 256;
      const int key = c & 63, hc = c >> 6;
      bf16x8_t vv = *reinterpret_cast<const bf16x8_t*>(
          kv + (size_t)(b * S_ + kt0 + key) * 2048 + 1024 + hkv * 128 + hc * 8);
#pragma unroll
      for (int e = 0; e < 8; e++) Vt[(hc * 8 + e) * 68 + key] = vv[e];
    }
    __syncthreads();

    // S = Q K^T
    f32x4_t s_acc[2][4] = {};
#pragma unroll
    for (int ks = 0; ks < 4; ks++) {
      bf16x8_t kf[4];
#pragma unroll
      for (int t = 0; t < 4; t++)
        kf[t] = *reinterpret_cast<const bf16x8_t*>(&Ks[(t * 16 + lo) * 132 + ks * 32 + hi * 8]);
#pragma unroll
      for (int mi = 0; mi < 2; mi++)
#pragma unroll
        for (int t = 0; t < 4; t++)
          s_acc[mi][t] = __builtin_amdgcn_mfma_f32_16x16x32_bf16(qf[mi][ks], kf[t], s_acc[mi][t], 0, 0, 0);
    }

#pragma unroll
    for (int mi = 0; mi < 2; mi++) {
      const int rowbase = q0 + w * 32 + mi * 16;
      // mask needed iff max key (kt0+63) exceeds min row (rowbase)  [R2 bug: compared
      // against rowbase+15, leaving diagonal frags with rowbase==kt0+48 unmasked]
      const bool need_mask = (kt0 + 63) > rowbase;  // wave-uniform
      float sv[4][4];
#pragma unroll
      for (int t = 0; t < 4; t++)
#pragma unroll
        for (int r = 0; r < 4; r++) {
          float val = s_acc[mi][t][r] * SC;
          if (need_mask && (kt0 + t * 16 + lo) > (rowbase + hi * 4 + r)) val = -1e30f;
          sv[t][r] = val;
        }
      float alpha[4], mnew[4];
#pragma unroll
      for (int r = 0; r < 4; r++) {
        float mx = fmaxf(fmaxf(sv[0][r], sv[1][r]), fmaxf(sv[2][r], sv[3][r]));
#pragma unroll
        for (int off = 1; off < 16; off <<= 1) mx = fmaxf(mx, __shfl_xor(mx, off));
        mnew[r] = fmaxf(m_prev[mi][r], mx);
        alpha[r] = __builtin_amdgcn_exp2f(m_prev[mi][r] - mnew[r]);
        m_prev[mi][r] = mnew[r];
      }
#pragma unroll
      for (int t = 0; t < 4; t++)
#pragma unroll
        for (int r = 0; r < 4; r++)
          Ps[w][(mi * 16 + hi * 4 + r) * 68 + t * 16 + lo] =
              (__bf16)__builtin_amdgcn_exp2f(sv[t][r] - mnew[r]);
#pragma unroll
      for (int t8 = 0; t8 < 8; t8++)
#pragma unroll
        for (int r = 0; r < 4; r++) o_acc[mi][t8][r] *= alpha[r];
#pragma unroll
      for (int r = 0; r < 4; r++) l_acc[mi][r] *= alpha[r];
    }

    // O += P V ; l += P . 1   (in-wave LDS write->read, compiler orders lgkmcnt)
#pragma unroll
    for (int ks2 = 0; ks2 < 2; ks2++) {
      bf16x8_t pf[2];
#pragma unroll
      for (int mi = 0; mi < 2; mi++)
        pf[mi] = *reinterpret_cast<const bf16x8_t*>(&Ps[w][(mi * 16 + lo) * 68 + ks2 * 32 + hi * 8]);
#pragma unroll
      for (int mi = 0; mi < 2; mi++)
        l_acc[mi] = __builtin_amdgcn_mfma_f32_16x16x32_bf16(pf[mi], ones, l_acc[mi], 0, 0, 0);
#pragma unroll
      for (int t8 = 0; t8 < 8; t8++) {
        bf16x8_t vf = *reinterpret_cast<const bf16x8_t*>(&Vt[(t8 * 16 + lo) * 68 + ks2 * 32 + hi * 8]);
#pragma unroll
        for (int mi = 0; mi < 2; mi++)
          o_acc[mi][t8] = __builtin_amdgcn_mfma_f32_16x16x32_bf16(pf[mi], vf, o_acc[mi][t8], 0, 0, 0);
      }
    }
  }

  // epilogue
#pragma unroll
  for (int mi = 0; mi < 2; mi++)
#pragma unroll
    for (int r = 0; r < 4; r++) {
      const float inv = 1.0f / l_acc[mi][r];
      const int qr = q0 + w * 32 + mi * 16 + hi * 4 + r;
      const size_t obase = ((size_t)(b * S_ + qr) * NH_ + h) * HD_;
#pragma unroll
      for (int t8 = 0; t8 < 8; t8++)
        o[obase + t8 * 16 + lo] = (__bf16)(o_acc[mi][t8][r] * inv);
    }
}

extern "C" void kernel_launch(void* const* d_in, const int* in_sizes, int n_in,
                              void* d_out, int out_size, void* d_ws, size_t ws_size,
                              hipStream_t stream) {
  const float* x = (const float*)d_in[0];
  const float* wq = (const float*)d_in[1];
  const float* wk = (const float*)d_in[2];
  const float* wv = (const float*)d_in[3];
  const float* wo = (const float*)d_in[4];
  const float* fcos = (const float*)d_in[5];
  const float* fsin = (const float*)d_in[6];
  float* out = (float*)d_out;

  // ws layout (bytes): [0,32M) xb then wob ; [32M,80M) wqkv then ab@[32M,64M)
  //                    [80M,112M) qb ; [112M,128M) kvb.  Peak 128 MiB.
  __bf16* xb   = (__bf16*)d_ws;                              // 16.7M elts
  __bf16* wqkv = xb + (size_t)16777216;                      // 25.2M elts (wq|wk|wv rows)
  __bf16* qb   = (__bf16*)d_ws + (size_t)41943040;           // (M,NH,HD) 16.7M
  __bf16* kvb  = qb + (size_t)16777216;                      // (M,2048): K|V per row, 8.4M
  __bf16* wob  = xb;                                         // reuses xb after QKV GEMM
  __bf16* ab   = wqkv;                                       // reuses wqkv after QKV GEMM

  convert_main<<<20480, 256, 0, stream>>>(x, wq, wk, wv, xb, wqkv);
  gemm_bt<true, false><<<dim3(48, 32), 256, 0, stream>>>(xb, wqkv, qb, kvb, 6144, D_);
  convert_wo<<<8192, 256, 0, stream>>>(wo, wob);
  rope_kernel<<<(M_ * (NH_ + NKV_) * (HD_ / 2)) / 256, 256, 0, stream>>>(qb, kvb, fcos, fsin);
  attn_kernel<<<dim3(S_ / 128, NH_, B_), 256, 0, stream>>>(qb, kvb, ab);
  gemm_bt<false, true><<<dim3(32, 32), 256, 0, stream>>>(ab, wob, out, nullptr, D_, D_);
}